// Round 3
// baseline (291.043 us; speedup 1.0000x reference)
//
#include <hip/hip_runtime.h>

#define N_NODES 2000
#define BATCH   32
#define DIM     64      // DIM_IN == DIM_OUT
#define EMB     16
#define KI      192     // CHEB_K * DIM_IN

typedef __bf16 bf16;
typedef __attribute__((ext_vector_type(8))) __bf16 bf16x8;
typedef __attribute__((ext_vector_type(4))) float  f32x4;

struct alignas(8) bf16x4pk { bf16 v[4]; };

// ---------------------------------------------------------------------------
// Kernel 1: s = softmax(relu(nv1 @ nv2), axis=1)   [N,N], output bf16
// ---------------------------------------------------------------------------
__global__ __launch_bounds__(256) void adj_softmax_kernel(
    const float* __restrict__ nv1, const float* __restrict__ nv2,
    bf16* __restrict__ s)
{
    const int row = blockIdx.x;
    const int tid = threadIdx.x;
    __shared__ float sa[EMB];
    __shared__ float z[N_NODES];
    __shared__ float wred[4];
    __shared__ float bcast;
    if (tid < EMB) sa[tid] = nv1[row * EMB + tid];
    __syncthreads();

    float lmax = 0.0f;
    for (int j = tid; j < N_NODES; j += 256) {
        float acc = 0.0f;
#pragma unroll
        for (int d = 0; d < EMB; ++d) acc += sa[d] * nv2[d * N_NODES + j];
        acc = fmaxf(acc, 0.0f);
        z[j] = acc;
        lmax = fmaxf(lmax, acc);
    }
#pragma unroll
    for (int off = 32; off > 0; off >>= 1)
        lmax = fmaxf(lmax, __shfl_down(lmax, off, 64));
    if ((tid & 63) == 0) wred[tid >> 6] = lmax;
    __syncthreads();
    if (tid == 0) bcast = fmaxf(fmaxf(wred[0], wred[1]), fmaxf(wred[2], wred[3]));
    __syncthreads();
    const float rmax = bcast;

    float lsum = 0.0f;
    for (int j = tid; j < N_NODES; j += 256) {
        float e = __expf(z[j] - rmax);
        z[j] = e;
        lsum += e;
    }
#pragma unroll
    for (int off = 32; off > 0; off >>= 1)
        lsum += __shfl_down(lsum, off, 64);
    if ((tid & 63) == 0) wred[tid >> 6] = lsum;
    __syncthreads();
    if (tid == 0) bcast = wred[0] + wred[1] + wred[2] + wred[3];
    __syncthreads();
    const float inv = 1.0f / bcast;
    for (int j = tid; j < N_NODES; j += 256)
        s[(size_t)row * N_NODES + j] = (bf16)(z[j] * inv);
}

// ---------------------------------------------------------------------------
// Kernel 2: transpose+cast x [b][m][c] fp32 -> xT [b][c][m] bf16
// ---------------------------------------------------------------------------
__global__ __launch_bounds__(256) void transpose_cast_x(
    const float* __restrict__ X, bf16* __restrict__ Xt)
{
    const int b  = blockIdx.y;
    const int m0 = blockIdx.x * 64;
    const int tid = threadIdx.x;
    __shared__ bf16 T[64][72];
#pragma unroll
    for (int i = 0; i < 4; ++i) {
        int idx = i * 256 + tid;
        int r  = idx >> 4;
        int c4 = (idx & 15) * 4;
        float4 v = make_float4(0.f, 0.f, 0.f, 0.f);
        if (m0 + r < N_NODES)
            v = *(const float4*)&X[((size_t)b * N_NODES + m0 + r) * DIM + c4];
        T[c4 + 0][r] = (bf16)v.x;
        T[c4 + 1][r] = (bf16)v.y;
        T[c4 + 2][r] = (bf16)v.z;
        T[c4 + 3][r] = (bf16)v.w;
    }
    __syncthreads();
#pragma unroll
    for (int i = 0; i < 4; ++i) {
        int idx = i * 256 + tid;
        int c  = idx >> 4;
        int mc = idx & 15;
        if (m0 + mc * 4 + 4 <= N_NODES) {
            bf16x4pk pk;
            pk.v[0] = T[c][mc * 4 + 0];
            pk.v[1] = T[c][mc * 4 + 1];
            pk.v[2] = T[c][mc * 4 + 2];
            pk.v[3] = T[c][mc * 4 + 3];
            *(bf16x4pk*)&Xt[(size_t)(b * DIM + c) * N_NODES + m0 + mc * 4] = pk;
        }
    }
}

// ---------------------------------------------------------------------------
// Kernel 3: Y[b,n,c] = sum_m S[n,m] * X[b,m,c]  via mfma_f32_16x16x32_bf16
// ---------------------------------------------------------------------------
__global__ __launch_bounds__(256) void spmm_mfma(
    const bf16* __restrict__ S, const bf16* __restrict__ Bt,
    float* __restrict__ Y, bf16* __restrict__ Yt, int write_yt)
{
    const int b   = blockIdx.x;
    const int n0  = blockIdx.y * 64;
    const int tid = threadIdx.x;
    const int lane = tid & 63;
    const int wave = tid >> 6;
    const int wm = wave >> 1, wn = wave & 1;
    const int l15 = lane & 15, quad = lane >> 4;

    __shared__ bf16 As[64][40];
    __shared__ bf16 Bs[64][40];

    f32x4 acc[2][2] = {};

    const int srow = tid >> 2;
    const int soff = (tid & 3) * 8;
    const bf16* Btb = Bt + (size_t)b * DIM * N_NODES;

    for (int k0 = 0; k0 < N_NODES; k0 += 32) {
        const int an = n0 + srow;
        const int kk = k0 + soff;
        bf16x8 av = {}, bv = {};
        const bool kok = (kk + 8 <= N_NODES);
        if (kok && an < N_NODES)
            av = *(const bf16x8*)&S[(size_t)an * N_NODES + kk];
        if (kok)
            bv = *(const bf16x8*)&Btb[(size_t)srow * N_NODES + kk];
        __syncthreads();
        *(bf16x8*)&As[srow][soff] = av;
        *(bf16x8*)&Bs[srow][soff] = bv;
        __syncthreads();

        bf16x8 af[2], bfr[2];
#pragma unroll
        for (int rt = 0; rt < 2; ++rt)
            af[rt] = *(const bf16x8*)&As[wm * 32 + rt * 16 + l15][quad * 8];
#pragma unroll
        for (int ct = 0; ct < 2; ++ct)
            bfr[ct] = *(const bf16x8*)&Bs[wn * 32 + ct * 16 + l15][quad * 8];
#pragma unroll
        for (int rt = 0; rt < 2; ++rt)
#pragma unroll
            for (int ct = 0; ct < 2; ++ct)
                acc[rt][ct] = __builtin_amdgcn_mfma_f32_16x16x32_bf16(
                    af[rt], bfr[ct], acc[rt][ct], 0, 0, 0);
    }

#pragma unroll
    for (int rt = 0; rt < 2; ++rt) {
        const int nbase = n0 + wm * 32 + rt * 16 + quad * 4;
#pragma unroll
        for (int ct = 0; ct < 2; ++ct) {
            const int c = wn * 32 + ct * 16 + l15;
#pragma unroll
            for (int r = 0; r < 4; ++r) {
                int n = nbase + r;
                if (n < N_NODES)
                    Y[((size_t)b * N_NODES + n) * DIM + c] = acc[rt][ct][r];
            }
            if (write_yt && nbase + 4 <= N_NODES) {
                bf16x4pk pk;
                pk.v[0] = (bf16)acc[rt][ct][0];
                pk.v[1] = (bf16)acc[rt][ct][1];
                pk.v[2] = (bf16)acc[rt][ct][2];
                pk.v[3] = (bf16)acc[rt][ct][3];
                *(bf16x4pk*)&Yt[(size_t)(b * DIM + c) * N_NODES + nbase] = pk;
            }
        }
    }
}

// ---------------------------------------------------------------------------
// Kernel 4a: wpT[d*64+o][cheb*64+i] bf16  <-  wp[d][cheb][i][o] fp32
// ---------------------------------------------------------------------------
__global__ __launch_bounds__(256) void prep_wpT(
    const float* __restrict__ wp, bf16* __restrict__ wpT)
{
    int idx = blockIdx.x * 256 + threadIdx.x;   // 0 .. 16*64*192-1
    int k   = idx % KI;          // cheb*64+i
    int row = idx / KI;          // d*64+o
    int o = row & 63, d = row >> 6;
    int cheb = k >> 6, i = k & 63;
    wpT[idx] = (bf16)wp[(((d * 3 + cheb) * 64 + i) * 64) + o];
}

// ---------------------------------------------------------------------------
// Kernel 4: combine via MFMA.
//   out[g,o] = sum_d emb[n,d] * ( sum_k xg[g,k] * wpT[d*64+o, k] ) + bias[n,o]
// g = b*2000+n (rows of x/y1/y2/out are exactly flat [g][c]).
// Block: 64 rows x 1024 cols (16 d-chunks of 64). K = 192 exact (6 k-steps).
// A-frags held in registers across all chunks; B read straight from L2
// (wpT is 384 KB, L2-resident) -> the d-loop has NO barriers, NO LDS traffic.
// ---------------------------------------------------------------------------
__global__ __launch_bounds__(256) void combine_mfma(
    const float* __restrict__ x,  const float* __restrict__ y1,
    const float* __restrict__ y2, const float* __restrict__ emb,
    const bf16* __restrict__ wpT, const float* __restrict__ bp,
    float* __restrict__ out)
{
    const int g0  = blockIdx.x * 64;
    const int tid = threadIdx.x;
    const int lane = tid & 63, wave = tid >> 6;
    const int wm = wave >> 1, wn = wave & 1;
    const int l15 = lane & 15, quad = lane >> 4;

    __shared__ bf16 As[64][200];      // [row][k], stride 200 -> 2-way alias only
    __shared__ float emb_s[64][16];
    __shared__ float bp_s[EMB * 64];

    // stage emb rows (n = g % 2000)
    {
        int r = tid >> 2, d4 = (tid & 3) * 4;
        int n = (g0 + r) % N_NODES;
        *(float4*)&emb_s[r][d4] = *(const float4*)&emb[n * EMB + d4];
    }
    // stage bias_pool [16][64]
    *(float4*)&bp_s[tid * 4] = *(const float4*)&bp[tid * 4];

    // build A tile: xg = { x, y1, 2*y2 - x }
    {
        int r  = tid >> 2;
        int c0 = (tid & 3) * 16;
        size_t base = (size_t)(g0 + r) * DIM;
#pragma unroll
        for (int j = 0; j < 4; ++j) {
            int c = c0 + j * 4;
            float4 vx = *(const float4*)&x [base + c];
            float4 v1 = *(const float4*)&y1[base + c];
            float4 v2 = *(const float4*)&y2[base + c];
            bf16x4pk p0, p1, p2;
            p0.v[0] = (bf16)vx.x; p0.v[1] = (bf16)vx.y;
            p0.v[2] = (bf16)vx.z; p0.v[3] = (bf16)vx.w;
            p1.v[0] = (bf16)v1.x; p1.v[1] = (bf16)v1.y;
            p1.v[2] = (bf16)v1.z; p1.v[3] = (bf16)v1.w;
            p2.v[0] = (bf16)(2.0f * v2.x - vx.x);
            p2.v[1] = (bf16)(2.0f * v2.y - vx.y);
            p2.v[2] = (bf16)(2.0f * v2.z - vx.z);
            p2.v[3] = (bf16)(2.0f * v2.w - vx.w);
            *(bf16x4pk*)&As[r][c]       = p0;
            *(bf16x4pk*)&As[r][64 + c]  = p1;
            *(bf16x4pk*)&As[r][128 + c] = p2;
        }
    }
    __syncthreads();

    // A fragments -> registers (held across all 16 d-chunks)
    bf16x8 af[2][6];
#pragma unroll
    for (int rt = 0; rt < 2; ++rt)
#pragma unroll
        for (int ks = 0; ks < 6; ++ks)
            af[rt][ks] = *(const bf16x8*)&As[wm * 32 + rt * 16 + l15][ks * 32 + quad * 8];

    f32x4 facc[2][2] = {};
    for (int d = 0; d < EMB; ++d) {
        f32x4 acc[2][2] = {};
        const bf16* w0 = wpT + (size_t)(d * 64 + wn * 32 + l15) * KI + quad * 8;
#pragma unroll
        for (int ks = 0; ks < 6; ++ks) {
            bf16x8 b0 = *(const bf16x8*)&w0[ks * 32];
            bf16x8 b1 = *(const bf16x8*)&w0[16 * KI + ks * 32];
            acc[0][0] = __builtin_amdgcn_mfma_f32_16x16x32_bf16(af[0][ks], b0, acc[0][0], 0, 0, 0);
            acc[0][1] = __builtin_amdgcn_mfma_f32_16x16x32_bf16(af[0][ks], b1, acc[0][1], 0, 0, 0);
            acc[1][0] = __builtin_amdgcn_mfma_f32_16x16x32_bf16(af[1][ks], b0, acc[1][0], 0, 0, 0);
            acc[1][1] = __builtin_amdgcn_mfma_f32_16x16x32_bf16(af[1][ks], b1, acc[1][1], 0, 0, 0);
        }
#pragma unroll
        for (int rt = 0; rt < 2; ++rt)
#pragma unroll
            for (int r = 0; r < 4; ++r) {
                float w = emb_s[wm * 32 + rt * 16 + quad * 4 + r][d];
                facc[rt][0][r] += w * acc[rt][0][r];
                facc[rt][1][r] += w * acc[rt][1][r];
            }
    }

    // bias + store
#pragma unroll
    for (int rt = 0; rt < 2; ++rt) {
        const int rbase = wm * 32 + rt * 16 + quad * 4;
#pragma unroll
        for (int ct = 0; ct < 2; ++ct) {
            const int o = wn * 32 + ct * 16 + l15;
#pragma unroll
            for (int r = 0; r < 4; ++r) {
                float bsum = 0.0f;
#pragma unroll
                for (int d = 0; d < EMB; ++d)
                    bsum += emb_s[rbase + r][d] * bp_s[d * 64 + o];
                out[(size_t)(g0 + rbase + r) * DIM + o] = facc[rt][ct][r] + bsum;
            }
        }
    }
}

// ---------------------------------------------------------------------------
extern "C" void kernel_launch(void* const* d_in, const int* in_sizes, int n_in,
                              void* d_out, int out_size, void* d_ws, size_t ws_size,
                              hipStream_t stream) {
    const float* x   = (const float*)d_in[0];  // [32,2000,64]
    const float* emb = (const float*)d_in[1];  // [2000,16]
    const float* nv1 = (const float*)d_in[2];  // [2000,16]
    const float* nv2 = (const float*)d_in[3];  // [16,2000]
    const float* wp  = (const float*)d_in[4];  // [16,3,64,64]
    const float* bp  = (const float*)d_in[5];  // [16,64]
    float* out = (float*)d_out;                // [32,2000,64]

    char* w = (char*)d_ws;
    bf16*  s_bf = (bf16*)w;               w += (size_t)N_NODES * N_NODES * 2;
    bf16*  xT   = (bf16*)w;               w += (size_t)BATCH * DIM * N_NODES * 2;
    bf16*  y1T  = (bf16*)w;               w += (size_t)BATCH * DIM * N_NODES * 2;
    float* y1   = (float*)w;              w += (size_t)BATCH * N_NODES * DIM * 4;
    float* y2   = (float*)w;              w += (size_t)BATCH * N_NODES * DIM * 4;
    bf16*  wpT  = (bf16*)w;               // 16*64*192*2 = 393,216 B

    adj_softmax_kernel<<<N_NODES, 256, 0, stream>>>(nv1, nv2, s_bf);
    transpose_cast_x<<<dim3(32, BATCH), 256, 0, stream>>>(x, xT);
    prep_wpT<<<(EMB * 64 * KI) / 256, 256, 0, stream>>>(wp, wpT);
    spmm_mfma<<<dim3(BATCH, 32), 256, 0, stream>>>(s_bf, xT,  y1, y1T, 1);
    spmm_mfma<<<dim3(BATCH, 32), 256, 0, stream>>>(s_bf, y1T, y2, y1T, 0);
    combine_mfma<<<(BATCH * N_NODES) / 64, 256, 0, stream>>>(
        x, y1, y2, emb, wpT, bp, out);
}

// Round 4
// 212.765 us; speedup vs baseline: 1.3679x; 1.3679x over previous
//
#include <hip/hip_runtime.h>

#define N_NODES 2000
#define BATCH   32
#define DIM     64      // DIM_IN == DIM_OUT
#define EMB     16
#define KI      192     // CHEB_K * DIM_IN
#define WCOLS   12288   // DIM_OUT * KI  (W row length per node)

typedef __bf16 bf16;
typedef __attribute__((ext_vector_type(8))) __bf16 bf16x8;
typedef __attribute__((ext_vector_type(4))) float  f32x4;

struct alignas(8) bf16x4pk { bf16 v[4]; };

// ---------------------------------------------------------------------------
// Kernel 1: s = softmax(relu(nv1 @ nv2), axis=1)   [N,N], output bf16
// ---------------------------------------------------------------------------
__global__ __launch_bounds__(256) void adj_softmax_kernel(
    const float* __restrict__ nv1, const float* __restrict__ nv2,
    bf16* __restrict__ s)
{
    const int row = blockIdx.x;
    const int tid = threadIdx.x;
    __shared__ float sa[EMB];
    __shared__ float z[N_NODES];
    __shared__ float wred[4];
    __shared__ float bcast;
    if (tid < EMB) sa[tid] = nv1[row * EMB + tid];
    __syncthreads();

    float lmax = 0.0f;
    for (int j = tid; j < N_NODES; j += 256) {
        float acc = 0.0f;
#pragma unroll
        for (int d = 0; d < EMB; ++d) acc += sa[d] * nv2[d * N_NODES + j];
        acc = fmaxf(acc, 0.0f);
        z[j] = acc;
        lmax = fmaxf(lmax, acc);
    }
#pragma unroll
    for (int off = 32; off > 0; off >>= 1)
        lmax = fmaxf(lmax, __shfl_down(lmax, off, 64));
    if ((tid & 63) == 0) wred[tid >> 6] = lmax;
    __syncthreads();
    if (tid == 0) bcast = fmaxf(fmaxf(wred[0], wred[1]), fmaxf(wred[2], wred[3]));
    __syncthreads();
    const float rmax = bcast;

    float lsum = 0.0f;
    for (int j = tid; j < N_NODES; j += 256) {
        float e = __expf(z[j] - rmax);
        z[j] = e;
        lsum += e;
    }
#pragma unroll
    for (int off = 32; off > 0; off >>= 1)
        lsum += __shfl_down(lsum, off, 64);
    if ((tid & 63) == 0) wred[tid >> 6] = lsum;
    __syncthreads();
    if (tid == 0) bcast = wred[0] + wred[1] + wred[2] + wred[3];
    __syncthreads();
    const float inv = 1.0f / bcast;
    for (int j = tid; j < N_NODES; j += 256)
        s[(size_t)row * N_NODES + j] = (bf16)(z[j] * inv);
}

// ---------------------------------------------------------------------------
// Kernel 2: transpose+cast x [b][m][c] fp32 -> xT [b][c][m] bf16
// ---------------------------------------------------------------------------
__global__ __launch_bounds__(256) void transpose_cast_x(
    const float* __restrict__ X, bf16* __restrict__ Xt)
{
    const int b  = blockIdx.y;
    const int m0 = blockIdx.x * 64;
    const int tid = threadIdx.x;
    __shared__ bf16 T[64][72];
#pragma unroll
    for (int i = 0; i < 4; ++i) {
        int idx = i * 256 + tid;
        int r  = idx >> 4;
        int c4 = (idx & 15) * 4;
        float4 v = make_float4(0.f, 0.f, 0.f, 0.f);
        if (m0 + r < N_NODES)
            v = *(const float4*)&X[((size_t)b * N_NODES + m0 + r) * DIM + c4];
        T[c4 + 0][r] = (bf16)v.x;
        T[c4 + 1][r] = (bf16)v.y;
        T[c4 + 2][r] = (bf16)v.z;
        T[c4 + 3][r] = (bf16)v.w;
    }
    __syncthreads();
#pragma unroll
    for (int i = 0; i < 4; ++i) {
        int idx = i * 256 + tid;
        int c  = idx >> 4;
        int mc = idx & 15;
        if (m0 + mc * 4 + 4 <= N_NODES) {
            bf16x4pk pk;
            pk.v[0] = T[c][mc * 4 + 0];
            pk.v[1] = T[c][mc * 4 + 1];
            pk.v[2] = T[c][mc * 4 + 2];
            pk.v[3] = T[c][mc * 4 + 3];
            *(bf16x4pk*)&Xt[(size_t)(b * DIM + c) * N_NODES + m0 + mc * 4] = pk;
        }
    }
}

// ---------------------------------------------------------------------------
// Kernel 3: Y[b,n,c] = sum_m S[n,m] * X[b,m,c]  via mfma_f32_16x16x32_bf16
// (unchanged, known-good)
// ---------------------------------------------------------------------------
__global__ __launch_bounds__(256) void spmm_mfma(
    const bf16* __restrict__ S, const bf16* __restrict__ Bt,
    float* __restrict__ Y, bf16* __restrict__ Yt, int write_yt)
{
    const int b   = blockIdx.x;
    const int n0  = blockIdx.y * 64;
    const int tid = threadIdx.x;
    const int lane = tid & 63;
    const int wave = tid >> 6;
    const int wm = wave >> 1, wn = wave & 1;
    const int l15 = lane & 15, quad = lane >> 4;

    __shared__ bf16 As[64][40];
    __shared__ bf16 Bs[64][40];

    f32x4 acc[2][2] = {};

    const int srow = tid >> 2;
    const int soff = (tid & 3) * 8;
    const bf16* Btb = Bt + (size_t)b * DIM * N_NODES;

    for (int k0 = 0; k0 < N_NODES; k0 += 32) {
        const int an = n0 + srow;
        const int kk = k0 + soff;
        bf16x8 av = {}, bv = {};
        const bool kok = (kk + 8 <= N_NODES);
        if (kok && an < N_NODES)
            av = *(const bf16x8*)&S[(size_t)an * N_NODES + kk];
        if (kok)
            bv = *(const bf16x8*)&Btb[(size_t)srow * N_NODES + kk];
        __syncthreads();
        *(bf16x8*)&As[srow][soff] = av;
        *(bf16x8*)&Bs[srow][soff] = bv;
        __syncthreads();

        bf16x8 af[2], bfr[2];
#pragma unroll
        for (int rt = 0; rt < 2; ++rt)
            af[rt] = *(const bf16x8*)&As[wm * 32 + rt * 16 + l15][quad * 8];
#pragma unroll
        for (int ct = 0; ct < 2; ++ct)
            bfr[ct] = *(const bf16x8*)&Bs[wn * 32 + ct * 16 + l15][quad * 8];
#pragma unroll
        for (int rt = 0; rt < 2; ++rt)
#pragma unroll
            for (int ct = 0; ct < 2; ++ct)
                acc[rt][ct] = __builtin_amdgcn_mfma_f32_16x16x32_bf16(
                    af[rt], bfr[ct], acc[rt][ct], 0, 0, 0);
    }

#pragma unroll
    for (int rt = 0; rt < 2; ++rt) {
        const int nbase = n0 + wm * 32 + rt * 16 + quad * 4;
#pragma unroll
        for (int ct = 0; ct < 2; ++ct) {
            const int c = wn * 32 + ct * 16 + l15;
#pragma unroll
            for (int r = 0; r < 4; ++r) {
                int n = nbase + r;
                if (n < N_NODES)
                    Y[((size_t)b * N_NODES + n) * DIM + c] = acc[rt][ct][r];
            }
            if (write_yt && nbase + 4 <= N_NODES) {
                bf16x4pk pk;
                pk.v[0] = (bf16)acc[rt][ct][0];
                pk.v[1] = (bf16)acc[rt][ct][1];
                pk.v[2] = (bf16)acc[rt][ct][2];
                pk.v[3] = (bf16)acc[rt][ct][3];
                *(bf16x4pk*)&Yt[(size_t)(b * DIM + c) * N_NODES + nbase] = pk;
            }
        }
    }
}

// ---------------------------------------------------------------------------
// Kernel 4a: small prep.
//   wpT2[col][d] = wp[d][cheb][i][o],  col = o*192 + cheb*64 + i, d padded to 32
//   embp[n][d]   = emb[n][d],          d padded to 32
// ---------------------------------------------------------------------------
__global__ __launch_bounds__(256) void prep_small(
    const float* __restrict__ wp, const float* __restrict__ emb,
    bf16* __restrict__ wpT2, bf16* __restrict__ embp)
{
    int idx = blockIdx.x * 256 + threadIdx.x;
    if (idx < WCOLS * 32) {
        int col = idx >> 5, d = idx & 31;
        int o  = col / KI;
        int kk = col - o * KI;
        int cheb = kk >> 6, i = kk & 63;
        float v = (d < EMB) ? wp[(((d * 3 + cheb) * 64 + i) * 64) + o] : 0.0f;
        wpT2[idx] = (bf16)v;
    } else {
        int j = idx - WCOLS * 32;          // 0 .. 2000*32-1
        int n = j >> 5, d = j & 31;
        float v = (d < EMB) ? emb[n * EMB + d] : 0.0f;
        embp[j] = (bf16)v;
    }
}

// ---------------------------------------------------------------------------
// Kernel 4b: W[n][col] = sum_d embp[n][d] * wpT2[col][d]   (bf16 out)
// GEMM [2000 x 16] @ [16 x 12288] via MFMA 16x16x32 (K zero-padded to 32).
// Block: 16 nodes x 256 cols; 4 waves x 4 col-tiles, 1 MFMA each.
// C staged in LDS -> fully coalesced 512 B row stores.
// ---------------------------------------------------------------------------
__global__ __launch_bounds__(256) void prep_W_mfma(
    const bf16* __restrict__ embp, const bf16* __restrict__ wpT2,
    bf16* __restrict__ W)
{
    const int colbase = blockIdx.x * 256;
    const int n0      = blockIdx.y * 16;
    const int tid  = threadIdx.x;
    const int lane = tid & 63, wave = tid >> 6;
    const int l15 = lane & 15, quad = lane >> 4;

    __shared__ bf16 Cs[16][264];

    const bf16x8 af = *(const bf16x8*)&embp[(n0 + l15) * 32 + quad * 8];
    const f32x4 zero = {};
#pragma unroll
    for (int ct = 0; ct < 4; ++ct) {
        const int col = colbase + wave * 64 + ct * 16 + l15;
        bf16x8 bfr = *(const bf16x8*)&wpT2[(size_t)col * 32 + quad * 8];
        f32x4 acc = __builtin_amdgcn_mfma_f32_16x16x32_bf16(af, bfr, zero, 0, 0, 0);
#pragma unroll
        for (int r = 0; r < 4; ++r)
            Cs[quad * 4 + r][wave * 64 + ct * 16 + l15] = (bf16)acc[r];
    }
    __syncthreads();
    {
        const int row = tid >> 4;
        const int c16 = (tid & 15) * 16;
        bf16x8 v0 = *(const bf16x8*)&Cs[row][c16];
        bf16x8 v1 = *(const bf16x8*)&Cs[row][c16 + 8];
        bf16* dst = &W[(size_t)(n0 + row) * WCOLS + colbase + c16];
        *(bf16x8*)dst       = v0;
        *(bf16x8*)(dst + 8) = v1;
    }
}

// ---------------------------------------------------------------------------
// Kernel 5: per-node combine, exact contraction via MFMA.
//   out[b,n,o] = sum_k xg[b,n,k] * W[n][o*192+k] + bias[n,o]
// One block per node. A = xg [32 x 192] bf16 LDS; B = W_n as [o][k] LDS.
// 4 waves: wave w owns o-tile w*16, both m-tiles (batches 0-15 / 16-31).
// 48 MFMAs/block total; traffic-bound (~114 MB total over 2000 blocks).
// ---------------------------------------------------------------------------
__global__ __launch_bounds__(256) void combine_node(
    const float* __restrict__ x,  const float* __restrict__ y1,
    const float* __restrict__ y2, const float* __restrict__ emb,
    const float* __restrict__ bp, const bf16* __restrict__ W,
    float* __restrict__ out)
{
    const int n   = blockIdx.x;
    const int tid = threadIdx.x;
    const int lane = tid & 63, wave = tid >> 6;
    const int l15 = lane & 15, quad = lane >> 4;

    __shared__ bf16 As[BATCH][200];   // [b][k], stride 400 B -> 2-way alias only
    __shared__ bf16 Ws[DIM][200];     // [o][k]
    __shared__ float bias_s[DIM];
    __shared__ float emb_s[EMB];

    if (tid < EMB) emb_s[tid] = emb[n * EMB + tid];

    // --- stage A: xg rows for this node, all 32 batches ---
    {
        const int b  = tid >> 3;
        const int c8 = (tid & 7) * 8;
        const size_t base = ((size_t)b * N_NODES + n) * DIM + c8;
        float4 x0 = *(const float4*)&x [base], x1 = *(const float4*)&x [base + 4];
        float4 a0 = *(const float4*)&y1[base], a1 = *(const float4*)&y1[base + 4];
        float4 b0 = *(const float4*)&y2[base], b1 = *(const float4*)&y2[base + 4];
        bf16x8 px, p1, p2;
        px[0]=(bf16)x0.x; px[1]=(bf16)x0.y; px[2]=(bf16)x0.z; px[3]=(bf16)x0.w;
        px[4]=(bf16)x1.x; px[5]=(bf16)x1.y; px[6]=(bf16)x1.z; px[7]=(bf16)x1.w;
        p1[0]=(bf16)a0.x; p1[1]=(bf16)a0.y; p1[2]=(bf16)a0.z; p1[3]=(bf16)a0.w;
        p1[4]=(bf16)a1.x; p1[5]=(bf16)a1.y; p1[6]=(bf16)a1.z; p1[7]=(bf16)a1.w;
        p2[0]=(bf16)(2.0f*b0.x - x0.x); p2[1]=(bf16)(2.0f*b0.y - x0.y);
        p2[2]=(bf16)(2.0f*b0.z - x0.z); p2[3]=(bf16)(2.0f*b0.w - x0.w);
        p2[4]=(bf16)(2.0f*b1.x - x1.x); p2[5]=(bf16)(2.0f*b1.y - x1.y);
        p2[6]=(bf16)(2.0f*b1.z - x1.z); p2[7]=(bf16)(2.0f*b1.w - x1.w);
        *(bf16x8*)&As[b][c8]       = px;
        *(bf16x8*)&As[b][64 + c8]  = p1;
        *(bf16x8*)&As[b][128 + c8] = p2;
    }
    // --- stage B: W_n rows [o][k], fully coalesced global reads ---
    {
        const bf16* Wn = W + (size_t)n * WCOLS;
#pragma unroll
        for (int jj = 0; jj < 6; ++jj) {
            int chunk = jj * 256 + tid;        // 0..1535 (8-elem chunks)
            int o  = chunk / 24;
            int kc = chunk - o * 24;
            bf16x8 v = *(const bf16x8*)&Wn[(size_t)chunk * 8];
            *(bf16x8*)&Ws[o][kc * 8] = v;
        }
    }
    __syncthreads();

    if (tid < DIM) {
        float s = 0.0f;
#pragma unroll
        for (int d = 0; d < EMB; ++d) s += emb_s[d] * bp[d * DIM + tid];
        bias_s[tid] = s;
    }

    // --- fragments & MFMA ---
    bf16x8 af[2][6];
#pragma unroll
    for (int mt = 0; mt < 2; ++mt)
#pragma unroll
        for (int ks = 0; ks < 6; ++ks)
            af[mt][ks] = *(const bf16x8*)&As[mt * 16 + l15][ks * 32 + quad * 8];

    f32x4 acc[2] = {};
#pragma unroll
    for (int ks = 0; ks < 6; ++ks) {
        bf16x8 bfr = *(const bf16x8*)&Ws[wave * 16 + l15][ks * 32 + quad * 8];
        acc[0] = __builtin_amdgcn_mfma_f32_16x16x32_bf16(af[0][ks], bfr, acc[0], 0, 0, 0);
        acc[1] = __builtin_amdgcn_mfma_f32_16x16x32_bf16(af[1][ks], bfr, acc[1], 0, 0, 0);
    }
    __syncthreads();   // bias_s ready

    const int o = wave * 16 + l15;
    const float bv = bias_s[o];
#pragma unroll
    for (int mt = 0; mt < 2; ++mt)
#pragma unroll
        for (int r = 0; r < 4; ++r) {
            int b = mt * 16 + quad * 4 + r;
            out[((size_t)b * N_NODES + n) * DIM + o] = acc[mt][r] + bv;
        }
}

// ---------------------------------------------------------------------------
extern "C" void kernel_launch(void* const* d_in, const int* in_sizes, int n_in,
                              void* d_out, int out_size, void* d_ws, size_t ws_size,
                              hipStream_t stream) {
    const float* x   = (const float*)d_in[0];  // [32,2000,64]
    const float* emb = (const float*)d_in[1];  // [2000,16]
    const float* nv1 = (const float*)d_in[2];  // [2000,16]
    const float* nv2 = (const float*)d_in[3];  // [16,2000]
    const float* wp  = (const float*)d_in[4];  // [16,3,64,64]
    const float* bp  = (const float*)d_in[5];  // [16,64]
    float* out = (float*)d_out;                // [32,2000,64]

    char* w = (char*)d_ws;
    bf16*  s_bf = (bf16*)w;  w += (size_t)N_NODES * N_NODES * 2;        //  8.00 MB
    bf16*  xT   = (bf16*)w;  w += (size_t)BATCH * DIM * N_NODES * 2;    //  8.19 MB
    bf16*  y1T  = (bf16*)w;  w += (size_t)BATCH * DIM * N_NODES * 2;    //  8.19 MB
    float* y1   = (float*)w; w += (size_t)BATCH * N_NODES * DIM * 4;    // 16.38 MB
    float* y2   = (float*)w; w += (size_t)BATCH * N_NODES * DIM * 4;    // 16.38 MB
    bf16*  wpT2 = (bf16*)w;  w += (size_t)WCOLS * 32 * 2;               //  0.79 MB
    bf16*  embp = (bf16*)w;  w += (size_t)N_NODES * 32 * 2;             //  0.13 MB
    bf16*  W    = (bf16*)w;                                             // 49.15 MB

    adj_softmax_kernel<<<N_NODES, 256, 0, stream>>>(nv1, nv2, s_bf);
    transpose_cast_x<<<dim3(32, BATCH), 256, 0, stream>>>(x, xT);
    prep_small<<<(WCOLS * 32 + N_NODES * 32) / 256, 256, 0, stream>>>(wp, emb, wpT2, embp);
    prep_W_mfma<<<dim3(WCOLS / 256, N_NODES / 16), 256, 0, stream>>>(embp, wpT2, W);
    spmm_mfma<<<dim3(BATCH, 32), 256, 0, stream>>>(s_bf, xT,  y1, y1T, 1);
    spmm_mfma<<<dim3(BATCH, 32), 256, 0, stream>>>(s_bf, y1T, y2, y1T, 0);
    combine_node<<<N_NODES, 256, 0, stream>>>(x, y1, y2, emb, bp, W, out);
}